// Round 10
// baseline (177.433 us; speedup 1.0000x reference)
//
#include <hip/hip_runtime.h>
#include <hip/hip_bf16.h>

#define T_SEQ 2048
#define D_DIM 1024
#define NB 4

typedef __attribute__((ext_vector_type(8))) short short8;
typedef __attribute__((ext_vector_type(4))) float f32x4;

__device__ __forceinline__ unsigned short f2bf(float f) {
    unsigned int u = __float_as_uint(f);
    u = (u + 0x7FFFu + ((u >> 16) & 1u)) >> 16;
    return (unsigned short)u;
}

__global__ void cast_kernel(const float4* __restrict__ in, ushort4* __restrict__ out, int n4) {
    int i = blockIdx.x * 256 + threadIdx.x;
    if (i < n4) {
        float4 f = in[i];
        ushort4 o;
        o.x = f2bf(f.x); o.y = f2bf(f.y); o.z = f2bf(f.z); o.w = f2bf(f.w);
        out[i] = o;
    }
}

// Wq|Wk|Wv in one launch.
__global__ void cast3_kernel(const float4* __restrict__ wq, const float4* __restrict__ wk,
                             const float4* __restrict__ wv, ushort4* __restrict__ out) {
    const int w = blockIdx.x >> 10;
    const int i = (blockIdx.x & 1023) * 256 + threadIdx.x;
    const float4* src = (w == 0) ? wq : (w == 1) ? wk : wv;
    float4 f = src[i];
    ushort4 o;
    o.x = f2bf(f.x); o.y = f2bf(f.y); o.z = f2bf(f.z); o.w = f2bf(f.w);
    out[w * 262144 + i] = o;
}

#define GLD(gp, lp) __builtin_amdgcn_global_load_lds( \
    (__attribute__((address_space(1))) void*)(gp), \
    (__attribute__((address_space(3))) void*)(lp), 16, 0, 0)

#define MFMA_BF16 __builtin_amdgcn_mfma_f32_16x16x32_bf16

// ===========================================================================
// 8-phase 256x256 core (r7-proven, unchanged): used by qk_gemm256 / s_gemm256.
// ===========================================================================
#define LIDX(slot, ab, half, ks) ((((((slot)*2 + (ab))*2 + (half))*2 + (ks)) * 4096))

__device__ __forceinline__ void core256(const unsigned short* __restrict__ Ap,
                                        const unsigned short* __restrict__ Bp,
                                        int bmA, int bnB,
                                        unsigned short* __restrict__ L,
                                        f32x4 acc[8][4]) {
    const int tid  = threadIdx.x;
    const int lane = tid & 63;
    const int wave = tid >> 6;
    const int wm   = wave >> 2;
    const int wn   = wave & 3;
    const int bh   = wn >> 1;
    const int lo   = lane & 15;
    const int hi   = lane >> 4;

    const int srow   = tid >> 2;
    const int schoff = (((tid & 3) ^ ((srow >> 1) & 3)) << 3);
    const unsigned short* sA0 = Ap + (size_t)(bmA * 256 +       srow) * 1024 + schoff;
    const unsigned short* sA1 = Ap + (size_t)(bmA * 256 + 128 + srow) * 1024 + schoff;
    const unsigned short* sB0 = Bp + (size_t)(bnB * 256 +       srow) * 1024 + schoff;
    const unsigned short* sB1 = Bp + (size_t)(bnB * 256 + 128 + srow) * 1024 + schoff;
    const int dst8 = tid * 8;

    const int choff  = ((hi ^ ((lo >> 1) & 3)) << 3);
    const int alocal = lo * 32 + choff;
    const int blocal = ((wn & 1) * 64 + lo) * 32 + choff;

    GLD(sA0,       &L[LIDX(0,0,0,0) + dst8]);  GLD(sA1,       &L[LIDX(0,0,1,0) + dst8]);
    GLD(sB0,       &L[LIDX(0,1,0,0) + dst8]);  GLD(sB1,       &L[LIDX(0,1,1,0) + dst8]);
    GLD(sA0 + 32,  &L[LIDX(0,0,0,1) + dst8]);  GLD(sA1 + 32,  &L[LIDX(0,0,1,1) + dst8]);
    GLD(sB0 + 32,  &L[LIDX(0,1,0,1) + dst8]);  GLD(sB1 + 32,  &L[LIDX(0,1,1,1) + dst8]);
    GLD(sA0 + 64,  &L[LIDX(1,0,0,0) + dst8]);  GLD(sA1 + 64,  &L[LIDX(1,0,1,0) + dst8]);
    GLD(sB0 + 64,  &L[LIDX(1,1,0,0) + dst8]);  GLD(sB1 + 64,  &L[LIDX(1,1,1,0) + dst8]);
    asm volatile("s_waitcnt vmcnt(8)" ::: "memory");
    __builtin_amdgcn_s_barrier();

    const int nt = 16;
    for (int t = 0; t < nt; ++t) {
        const int cur = t & 1;
        const unsigned short* Ak0 = &L[LIDX(cur, 0, wm, 0)] + alocal;
        const unsigned short* Bk0 = &L[LIDX(cur, 1, bh, 0)] + blocal;
        const unsigned short* Ak1 = &L[LIDX(cur, 0, wm, 1)] + alocal;
        const unsigned short* Bk1 = &L[LIDX(cur, 1, bh, 1)] + blocal;
        short8 av[4], bv0[4], bv1[4];

        // phase 1: k0, mf0-3
#pragma unroll
        for (int m = 0; m < 4; ++m) av[m]  = *(const short8*)(Ak0 + m * 512);
#pragma unroll
        for (int n = 0; n < 4; ++n) bv0[n] = *(const short8*)(Bk0 + n * 512);
        if (t + 1 < nt) {
            const int ko = (t + 1) * 64 + 32;
            GLD(sA0 + ko, &L[LIDX(cur ^ 1, 0, 0, 1) + dst8]);
            GLD(sA1 + ko, &L[LIDX(cur ^ 1, 0, 1, 1) + dst8]);
        }
        __builtin_amdgcn_s_barrier();
        asm volatile("s_waitcnt lgkmcnt(0)" ::: "memory");
        __builtin_amdgcn_sched_barrier(0);
        __builtin_amdgcn_s_setprio(1);
#pragma unroll
        for (int m = 0; m < 4; ++m)
#pragma unroll
            for (int n = 0; n < 4; ++n)
                acc[m][n] = MFMA_BF16(av[m], bv0[n], acc[m][n], 0, 0, 0);
        __builtin_amdgcn_s_setprio(0);
        __builtin_amdgcn_s_barrier();

        // phase 2: k0, mf4-7
#pragma unroll
        for (int m = 0; m < 4; ++m) av[m] = *(const short8*)(Ak0 + (4 + m) * 512);
        if (t + 1 < nt) {
            const int ko = (t + 1) * 64 + 32;
            GLD(sB0 + ko, &L[LIDX(cur ^ 1, 1, 0, 1) + dst8]);
            GLD(sB1 + ko, &L[LIDX(cur ^ 1, 1, 1, 1) + dst8]);
        }
        if (t + 1 < nt) { asm volatile("s_waitcnt vmcnt(8)" ::: "memory"); }
        else            { asm volatile("s_waitcnt vmcnt(0)" ::: "memory"); }
        __builtin_amdgcn_s_barrier();
        asm volatile("s_waitcnt lgkmcnt(0)" ::: "memory");
        __builtin_amdgcn_sched_barrier(0);
        __builtin_amdgcn_s_setprio(1);
#pragma unroll
        for (int m = 0; m < 4; ++m)
#pragma unroll
            for (int n = 0; n < 4; ++n)
                acc[4 + m][n] = MFMA_BF16(av[m], bv0[n], acc[4 + m][n], 0, 0, 0);
        __builtin_amdgcn_s_setprio(0);
        __builtin_amdgcn_s_barrier();

        // phase 3: k1, mf0-3
#pragma unroll
        for (int m = 0; m < 4; ++m) av[m]  = *(const short8*)(Ak1 + m * 512);
#pragma unroll
        for (int n = 0; n < 4; ++n) bv1[n] = *(const short8*)(Bk1 + n * 512);
        if (t + 2 < nt) {
            const int ko = (t + 2) * 64;
            GLD(sA0 + ko, &L[LIDX(cur, 0, 0, 0) + dst8]);
            GLD(sA1 + ko, &L[LIDX(cur, 0, 1, 0) + dst8]);
        }
        __builtin_amdgcn_s_barrier();
        asm volatile("s_waitcnt lgkmcnt(0)" ::: "memory");
        __builtin_amdgcn_sched_barrier(0);
        __builtin_amdgcn_s_setprio(1);
#pragma unroll
        for (int m = 0; m < 4; ++m)
#pragma unroll
            for (int n = 0; n < 4; ++n)
                acc[m][n] = MFMA_BF16(av[m], bv1[n], acc[m][n], 0, 0, 0);
        __builtin_amdgcn_s_setprio(0);
        __builtin_amdgcn_s_barrier();

        // phase 4: k1, mf4-7
#pragma unroll
        for (int m = 0; m < 4; ++m) av[m] = *(const short8*)(Ak1 + (4 + m) * 512);
        if (t + 2 < nt) {
            const int ko = (t + 2) * 64;
            GLD(sB0 + ko, &L[LIDX(cur, 1, 0, 0) + dst8]);
            GLD(sB1 + ko, &L[LIDX(cur, 1, 1, 0) + dst8]);
        }
        if (t + 1 < nt) {
            if (t + 2 < nt) { asm volatile("s_waitcnt vmcnt(8)" ::: "memory"); }
            else            { asm volatile("s_waitcnt vmcnt(4)" ::: "memory"); }
        }
        __builtin_amdgcn_s_barrier();
        asm volatile("s_waitcnt lgkmcnt(0)" ::: "memory");
        __builtin_amdgcn_sched_barrier(0);
        __builtin_amdgcn_s_setprio(1);
#pragma unroll
        for (int m = 0; m < 4; ++m)
#pragma unroll
            for (int n = 0; n < 4; ++n)
                acc[4 + m][n] = MFMA_BF16(av[m], bv1[n], acc[4 + m][n], 0, 0, 0);
        __builtin_amdgcn_s_setprio(0);
        __builtin_amdgcn_s_barrier();
    }
}

// QK projection on the 8-phase core: grid 256 x 512thr.
__global__ __launch_bounds__(512, 2) void qk_gemm256(const unsigned short* __restrict__ xb,
                                                     const unsigned short* __restrict__ wb,
                                                     unsigned short* __restrict__ Qb,
                                                     unsigned short* __restrict__ Kb) {
    __shared__ __align__(16) unsigned short L[16 * 4096];
    const int lane = threadIdx.x & 63, wave = threadIdx.x >> 6;
    const int wm = wave >> 2, wn = wave & 3;
    const int lo = lane & 15, hi = lane >> 4;

    const int wg  = (blockIdx.x & 7) * 32 + (blockIdx.x >> 3);
    const int bmA = wg >> 3;
    const int bnB = wg & 7;

    f32x4 acc[8][4] = {};
    core256(xb, wb, bmA, bnB, L, acc);

    unsigned short* O = (bnB < 4) ? Qb : Kb;
    const int rb = bmA * 256 + wm * 128 + hi * 4;
    const int cb = (bnB & 3) * 256 + wn * 64 + lo;
#pragma unroll
    for (int mf = 0; mf < 8; ++mf)
#pragma unroll
        for (int nf = 0; nf < 4; ++nf)
#pragma unroll
            for (int r = 0; r < 4; ++r)
                O[(size_t)(rb + mf * 16 + r) * D_DIM + (cb + nf * 16)] = f2bf(acc[mf][nf][r]);
}

// S scores on the 8-phase core: grid 144 = 36 causal 256-tiles x 4 batches.
__global__ __launch_bounds__(512, 2) void s_gemm256(const unsigned short* __restrict__ Qb,
                                                    const unsigned short* __restrict__ Kb,
                                                    float* __restrict__ S) {
    __shared__ __align__(16) unsigned short L[16 * 4096];
    const int lane = threadIdx.x & 63, wave = threadIdx.x >> 6;
    const int wm = wave >> 2, wn = wave & 3;
    const int lo = lane & 15, hi = lane >> 4;

    const int wg = (blockIdx.x & 7) * 18 + (blockIdx.x >> 3);
    const int z  = wg / 36;
    int i = wg % 36;
    int bm = 0;
    while (i >= bm + 1) { i -= (bm + 1); ++bm; }
    const int bn = i;

    const unsigned short* Ap = Qb + (size_t)z * T_SEQ * D_DIM;
    const unsigned short* Bp = Kb + (size_t)z * T_SEQ * D_DIM;
    f32x4 acc[8][4] = {};
    core256(Ap, Bp, bm, bn, L, acc);

    float* Sp = S + (size_t)z * T_SEQ * T_SEQ;
    const float scale = 0.03125f;
    const int rb = bm * 256 + wm * 128 + hi * 4;
    const int cb = bn * 256 + wn * 64 + lo;
#pragma unroll
    for (int mf = 0; mf < 8; ++mf)
#pragma unroll
        for (int nf = 0; nf < 4; ++nf)
#pragma unroll
            for (int r = 0; r < 4; ++r) {
                const int row = rb + mf * 16 + r;
                const int col = cb + nf * 16;
                if (col <= row) Sp[(size_t)row * T_SEQ + col] = acc[mf][nf][r] * scale;
            }
}

// ---------------------------------------------------------------------------
// 128x128 core, SINGLE-BARRIER depth-3 pipeline (new this round).
// Per iter: ds_read(t) -> lgkm(0) -> MFMA(t) -> vmcnt(cert t+1) -> BAR ->
// STAGE(t+4 into buf (t+4)%5).  5 LDS buffers (80 KB; 512-block grids are
// 2 blocks/CU at 48 KB or 80 KB alike, so the extra depth is free).
// Safety: (a) stage target (t+4)%5 == (t-1)%5, whose reads were lgkm-retired
// before iter t-1's MFMA, which precedes iter t-1's barrier -> one barrier
// ago for ALL waves.  (b) reads of tile t+1 at iter t+1 are safe because
// every wave executed vmcnt(cert t+1) BEFORE the iter-t barrier.
// vmcnt accounting (4 GLDs/tile): outstanding after cert of t+1 = tiles
// t+2,t+3 -> vmcnt(8); tails 4/0.  nt >= 4 for all users (pv bm=0 -> nt=4).
// ---------------------------------------------------------------------------
__device__ __forceinline__ void gemm_core(const unsigned short* __restrict__ A,
                                          const unsigned short* __restrict__ B,
                                          int lda, int ldb, int bm, int bn, int kend,
                                          f32x4 acc[4][4]) {
    __shared__ __align__(16) unsigned short As[5][128 * 32];
    __shared__ __align__(16) unsigned short Bs[5][128 * 32];
    const int tid  = threadIdx.x;
    const int lane = tid & 63;
    const int wave = tid >> 6;
    const int wm   = (wave >> 1) * 64;
    const int wn   = (wave & 1) * 64;
    const int lo   = lane & 15;
    const int hi   = lane >> 4;
    const int r0   = tid >> 2;
    const int q0   = (((tid & 3) ^ ((r0 >> 1) & 3)) * 8);

    const unsigned short* Arow0 = A + (size_t)(bm * 128 + r0) * lda + q0;
    const unsigned short* Arow1 = A + (size_t)(bm * 128 + r0 + 64) * lda + q0;
    const unsigned short* Brow0 = B + (size_t)(bn * 128 + r0) * ldb + q0;
    const unsigned short* Brow1 = B + (size_t)(bn * 128 + r0 + 64) * ldb + q0;

#define STAGE(t, buf) do { const int kk_ = (t) << 5; \
        GLD(Arow0 + kk_, As[buf] + tid * 8); \
        GLD(Arow1 + kk_, As[buf] + (tid + 256) * 8); \
        GLD(Brow0 + kk_, Bs[buf] + tid * 8); \
        GLD(Brow1 + kk_, Bs[buf] + (tid + 256) * 8); } while (0)

    const int nt = kend >> 5;          // >= 4 for all callers
    STAGE(0, 0);
    STAGE(1, 1);
    STAGE(2, 2);
    STAGE(3, 3);

    int aoff[4], boff[4];
#pragma unroll
    for (int m = 0; m < 4; ++m) {
        const int ra = wm + m * 16 + lo;
        const int rb = wn + m * 16 + lo;
        aoff[m] = ra * 32 + ((hi ^ ((ra >> 1) & 3)) * 8);
        boff[m] = rb * 32 + ((hi ^ ((rb >> 1) & 3)) * 8);
    }

    asm volatile("s_waitcnt vmcnt(12)" ::: "memory");   // tile 0 landed (own lanes)
    __builtin_amdgcn_s_barrier();                       // ... for all waves
    __builtin_amdgcn_sched_barrier(0);

    int cur = 0;
    for (int t = 0; t < nt; ++t) {
        short8 av[4], bv[4];
#pragma unroll
        for (int m = 0; m < 4; ++m) av[m] = *(const short8*)&As[cur][aoff[m]];
#pragma unroll
        for (int n = 0; n < 4; ++n) bv[n] = *(const short8*)&Bs[cur][boff[n]];
        asm volatile("s_waitcnt lgkmcnt(0)" ::: "memory");
        __builtin_amdgcn_sched_barrier(0);              // MFMA stays below the drain

        __builtin_amdgcn_s_setprio(1);
#pragma unroll
        for (int m = 0; m < 4; ++m)
#pragma unroll
            for (int n = 0; n < 4; ++n)
                acc[m][n] = MFMA_BF16(av[m], bv[n], acc[m][n], 0, 0, 0);
        __builtin_amdgcn_s_setprio(0);

        if (t + 1 < nt) {                               // certify tile t+1 (pre-barrier!)
            if (t + 3 < nt)      { asm volatile("s_waitcnt vmcnt(8)" ::: "memory"); }
            else if (t + 2 < nt) { asm volatile("s_waitcnt vmcnt(4)" ::: "memory"); }
            else                 { asm volatile("s_waitcnt vmcnt(0)" ::: "memory"); }
        }
        __builtin_amdgcn_s_barrier();                   // publish cert + free buf (t-1)%5
        __builtin_amdgcn_sched_barrier(0);              // ds_read of t+1 stays below BAR
        if (t + 4 < nt) {
            int nb = cur + 4; if (nb >= 5) nb -= 5;
            STAGE(t + 4, nb);
        }
        cur += 1; if (cur >= 5) cur = 0;
    }
#undef STAGE
}

// V^T via operand swap: C[e][t] = sum_d Wv[e][d] x[t][d]; grid (64 t-blocks, 8 e-blocks).
__global__ __launch_bounds__(256) void v_gemm(const unsigned short* __restrict__ xb,
                                              const unsigned short* __restrict__ wv,
                                              unsigned short* __restrict__ Vt) {
    const int lane = threadIdx.x & 63, wave = threadIdx.x >> 6;
    f32x4 acc[4][4] = {};
    gemm_core(wv, xb, D_DIM, D_DIM, blockIdx.y, blockIdx.x, D_DIM, acc);
    const int rb = blockIdx.y * 128 + (wave >> 1) * 64 + ((lane >> 4) << 2);   // e
    const int cb = blockIdx.x * 128 + (wave & 1) * 64 + (lane & 15);           // t global
#pragma unroll
    for (int m = 0; m < 4; ++m)
#pragma unroll
        for (int n = 0; n < 4; ++n)
#pragma unroll
            for (int r = 0; r < 4; ++r) {
                const int e = rb + m * 16 + r;
                const int t = cb + n * 16;
                Vt[((size_t)(t >> 11) * D_DIM + e) * T_SEQ + (t & 2047)] = f2bf(acc[m][n][r]);
            }
}

// Wave-per-row softmax: 4 rows/block, row in registers, shuffle reductions.
__global__ __launch_bounds__(256) void softmax_kernel(const float* __restrict__ S,
                                                      unsigned short* __restrict__ P) {
    const int lane = threadIdx.x & 63, wave = threadIdx.x >> 6;
    const int row = blockIdx.x * 4 + wave;
    const int b = row >> 11, i = row & 2047;
    const float* srow = S + ((size_t)b * T_SEQ + i) * T_SEQ;
    unsigned short* prow = P + ((size_t)b * T_SEQ + i) * T_SEQ;
    const int len = i + 1;
    const int padlen = ((i >> 7) + 1) * 128;

    f32x4 v[8];
    float m = -1e30f;
#pragma unroll
    for (int c = 0; c < 8; ++c) {
        const int j0 = (c * 64 + lane) * 4;
        if (j0 < padlen) {
            v[c] = *(const f32x4*)(srow + j0);
#pragma unroll
            for (int e = 0; e < 4; ++e)
                if (j0 + e < len) m = fmaxf(m, v[c][e]);
        }
    }
#pragma unroll
    for (int off = 32; off; off >>= 1) m = fmaxf(m, __shfl_xor(m, off, 64));

    float s = 0.f;
#pragma unroll
    for (int c = 0; c < 8; ++c) {
        const int j0 = (c * 64 + lane) * 4;
        if (j0 < padlen) {
#pragma unroll
            for (int e = 0; e < 4; ++e) {
                float ev = (j0 + e < len) ? __expf(v[c][e] - m) : 0.f;
                v[c][e] = ev;
                s += ev;
            }
        }
    }
#pragma unroll
    for (int off = 32; off; off >>= 1) s += __shfl_xor(s, off, 64);
    const float inv = 1.f / s;

#pragma unroll
    for (int c = 0; c < 8; ++c) {
        const int j0 = (c * 64 + lane) * 4;
        if (j0 < padlen) {
            ushort4 o;
            o.x = f2bf(v[c][0] * inv);
            o.y = f2bf(v[c][1] * inv);
            o.z = f2bf(v[c][2] * inv);
            o.w = f2bf(v[c][3] * inv);
            *(ushort4*)(prow + j0) = o;
        }
    }
}

// Flat grid of 512 (all resident at 2/CU); causal K-bound kend=(bm+1)*128.
__global__ __launch_bounds__(256) void pv_gemm(const unsigned short* __restrict__ P,
                                               const unsigned short* __restrict__ Vt,
                                               float* __restrict__ Out) {
    const int d = blockIdx.x;
    const int j = d & 7;
    const int z = j >> 1;
    const int t = (j & 1) * 64 + (d >> 3);
    const int bm = 15 - (t >> 3), bn = t & 7;

    const unsigned short* Ap = P + (size_t)z * T_SEQ * T_SEQ;
    const unsigned short* Bp = Vt + (size_t)z * D_DIM * T_SEQ;
    f32x4 acc[4][4] = {};
    gemm_core(Ap, Bp, T_SEQ, T_SEQ, bm, bn, (bm + 1) * 128, acc);

    float* Op = Out + (size_t)z * T_SEQ * D_DIM;
    const int lane = threadIdx.x & 63, wave = threadIdx.x >> 6;
    const int rb = bm * 128 + (wave >> 1) * 64 + ((lane >> 4) << 2);
    const int cb = bn * 128 + (wave & 1) * 64 + (lane & 15);
#pragma unroll
    for (int m = 0; m < 4; ++m)
#pragma unroll
        for (int n = 0; n < 4; ++n)
#pragma unroll
            for (int r = 0; r < 4; ++r)
                Op[(size_t)(rb + m * 16 + r) * D_DIM + (cb + n * 16)] = acc[m][n][r];
}

extern "C" void kernel_launch(void* const* d_in, const int* in_sizes, int n_in,
                              void* d_out, int out_size, void* d_ws, size_t ws_size,
                              hipStream_t stream) {
    const float* x  = (const float*)d_in[0];
    const float* Wq = (const float*)d_in[1];
    const float* Wk = (const float*)d_in[2];
    const float* Wv = (const float*)d_in[3];
    float* out = (float*)d_out;
    char* ws = (char*)d_ws;

    unsigned short* xb = (unsigned short*)(ws);                 // 16 MB  x bf16 [8192,1024]
    unsigned short* wb = (unsigned short*)(ws + 16777216);      // 6 MB   Wq|Wk|Wv bf16
    unsigned short* Qb = (unsigned short*)(ws + 23068672);      // 16 MB
    unsigned short* Kb = (unsigned short*)(ws + 39845888);      // 16 MB
    unsigned short* Vt = (unsigned short*)(ws + 56623104);      // 16 MB  V^T per batch [1024][2048]
    float*          S  = (float*)(ws + 73400320);               // 64 MB  scores fp32
    unsigned short* P  = (unsigned short*)(ws + 140509184);     // 32 MB  probs bf16
    (void)ws_size; (void)in_sizes; (void)n_in; (void)out_size;

    cast_kernel<<<8192, 256, 0, stream>>>((const float4*)x, (ushort4*)xb, 2097152);
    cast3_kernel<<<3072, 256, 0, stream>>>((const float4*)Wq, (const float4*)Wk,
                                           (const float4*)Wv, (ushort4*)wb);

    qk_gemm256<<<256, 512, 0, stream>>>(xb, wb, Qb, Kb);
    v_gemm<<<dim3(64, 8), 256, 0, stream>>>(xb, wb + 2097152, Vt);
    s_gemm256<<<144, 512, 0, stream>>>(Qb, Kb, S);
    softmax_kernel<<<2048, 256, 0, stream>>>(S, P);
    pv_gemm<<<512, 256, 0, stream>>>(P, Vt, out);
}

// Round 11
// 163.272 us; speedup vs baseline: 1.0867x; 1.0867x over previous
//
#include <hip/hip_runtime.h>
#include <hip/hip_bf16.h>

#define T_SEQ 2048
#define D_DIM 1024
#define NB 4

typedef __attribute__((ext_vector_type(8))) short short8;
typedef __attribute__((ext_vector_type(4))) float f32x4;

__device__ __forceinline__ unsigned short f2bf(float f) {
    unsigned int u = __float_as_uint(f);
    u = (u + 0x7FFFu + ((u >> 16) & 1u)) >> 16;
    return (unsigned short)u;
}

__global__ void cast_kernel(const float4* __restrict__ in, ushort4* __restrict__ out, int n4) {
    int i = blockIdx.x * 256 + threadIdx.x;
    if (i < n4) {
        float4 f = in[i];
        ushort4 o;
        o.x = f2bf(f.x); o.y = f2bf(f.y); o.z = f2bf(f.z); o.w = f2bf(f.w);
        out[i] = o;
    }
}

// Wq|Wk|Wv in one launch.
__global__ void cast3_kernel(const float4* __restrict__ wq, const float4* __restrict__ wk,
                             const float4* __restrict__ wv, ushort4* __restrict__ out) {
    const int w = blockIdx.x >> 10;
    const int i = (blockIdx.x & 1023) * 256 + threadIdx.x;
    const float4* src = (w == 0) ? wq : (w == 1) ? wk : wv;
    float4 f = src[i];
    ushort4 o;
    o.x = f2bf(f.x); o.y = f2bf(f.y); o.z = f2bf(f.z); o.w = f2bf(f.w);
    out[w * 262144 + i] = o;
}

#define GLD(gp, lp) __builtin_amdgcn_global_load_lds( \
    (__attribute__((address_space(1))) void*)(gp), \
    (__attribute__((address_space(3))) void*)(lp), 16, 0, 0)

#define MFMA_BF16 __builtin_amdgcn_mfma_f32_16x16x32_bf16

// ===========================================================================
// 8-phase 256x256 core (r7-proven, unchanged): used by qk_gemm256 / s_gemm256.
// ===========================================================================
#define LIDX(slot, ab, half, ks) ((((((slot)*2 + (ab))*2 + (half))*2 + (ks)) * 4096))

__device__ __forceinline__ void core256(const unsigned short* __restrict__ Ap,
                                        const unsigned short* __restrict__ Bp,
                                        int bmA, int bnB,
                                        unsigned short* __restrict__ L,
                                        f32x4 acc[8][4]) {
    const int tid  = threadIdx.x;
    const int lane = tid & 63;
    const int wave = tid >> 6;
    const int wm   = wave >> 2;
    const int wn   = wave & 3;
    const int bh   = wn >> 1;
    const int lo   = lane & 15;
    const int hi   = lane >> 4;

    const int srow   = tid >> 2;
    const int schoff = (((tid & 3) ^ ((srow >> 1) & 3)) << 3);
    const unsigned short* sA0 = Ap + (size_t)(bmA * 256 +       srow) * 1024 + schoff;
    const unsigned short* sA1 = Ap + (size_t)(bmA * 256 + 128 + srow) * 1024 + schoff;
    const unsigned short* sB0 = Bp + (size_t)(bnB * 256 +       srow) * 1024 + schoff;
    const unsigned short* sB1 = Bp + (size_t)(bnB * 256 + 128 + srow) * 1024 + schoff;
    const int dst8 = tid * 8;

    const int choff  = ((hi ^ ((lo >> 1) & 3)) << 3);
    const int alocal = lo * 32 + choff;
    const int blocal = ((wn & 1) * 64 + lo) * 32 + choff;

    GLD(sA0,       &L[LIDX(0,0,0,0) + dst8]);  GLD(sA1,       &L[LIDX(0,0,1,0) + dst8]);
    GLD(sB0,       &L[LIDX(0,1,0,0) + dst8]);  GLD(sB1,       &L[LIDX(0,1,1,0) + dst8]);
    GLD(sA0 + 32,  &L[LIDX(0,0,0,1) + dst8]);  GLD(sA1 + 32,  &L[LIDX(0,0,1,1) + dst8]);
    GLD(sB0 + 32,  &L[LIDX(0,1,0,1) + dst8]);  GLD(sB1 + 32,  &L[LIDX(0,1,1,1) + dst8]);
    GLD(sA0 + 64,  &L[LIDX(1,0,0,0) + dst8]);  GLD(sA1 + 64,  &L[LIDX(1,0,1,0) + dst8]);
    GLD(sB0 + 64,  &L[LIDX(1,1,0,0) + dst8]);  GLD(sB1 + 64,  &L[LIDX(1,1,1,0) + dst8]);
    asm volatile("s_waitcnt vmcnt(8)" ::: "memory");
    __builtin_amdgcn_s_barrier();

    const int nt = 16;
    for (int t = 0; t < nt; ++t) {
        const int cur = t & 1;
        const unsigned short* Ak0 = &L[LIDX(cur, 0, wm, 0)] + alocal;
        const unsigned short* Bk0 = &L[LIDX(cur, 1, bh, 0)] + blocal;
        const unsigned short* Ak1 = &L[LIDX(cur, 0, wm, 1)] + alocal;
        const unsigned short* Bk1 = &L[LIDX(cur, 1, bh, 1)] + blocal;
        short8 av[4], bv0[4], bv1[4];

        // phase 1: k0, mf0-3
#pragma unroll
        for (int m = 0; m < 4; ++m) av[m]  = *(const short8*)(Ak0 + m * 512);
#pragma unroll
        for (int n = 0; n < 4; ++n) bv0[n] = *(const short8*)(Bk0 + n * 512);
        if (t + 1 < nt) {
            const int ko = (t + 1) * 64 + 32;
            GLD(sA0 + ko, &L[LIDX(cur ^ 1, 0, 0, 1) + dst8]);
            GLD(sA1 + ko, &L[LIDX(cur ^ 1, 0, 1, 1) + dst8]);
        }
        __builtin_amdgcn_s_barrier();
        asm volatile("s_waitcnt lgkmcnt(0)" ::: "memory");
        __builtin_amdgcn_sched_barrier(0);
        __builtin_amdgcn_s_setprio(1);
#pragma unroll
        for (int m = 0; m < 4; ++m)
#pragma unroll
            for (int n = 0; n < 4; ++n)
                acc[m][n] = MFMA_BF16(av[m], bv0[n], acc[m][n], 0, 0, 0);
        __builtin_amdgcn_s_setprio(0);
        __builtin_amdgcn_s_barrier();

        // phase 2: k0, mf4-7
#pragma unroll
        for (int m = 0; m < 4; ++m) av[m] = *(const short8*)(Ak0 + (4 + m) * 512);
        if (t + 1 < nt) {
            const int ko = (t + 1) * 64 + 32;
            GLD(sB0 + ko, &L[LIDX(cur ^ 1, 1, 0, 1) + dst8]);
            GLD(sB1 + ko, &L[LIDX(cur ^ 1, 1, 1, 1) + dst8]);
        }
        if (t + 1 < nt) { asm volatile("s_waitcnt vmcnt(8)" ::: "memory"); }
        else            { asm volatile("s_waitcnt vmcnt(0)" ::: "memory"); }
        __builtin_amdgcn_s_barrier();
        asm volatile("s_waitcnt lgkmcnt(0)" ::: "memory");
        __builtin_amdgcn_sched_barrier(0);
        __builtin_amdgcn_s_setprio(1);
#pragma unroll
        for (int m = 0; m < 4; ++m)
#pragma unroll
            for (int n = 0; n < 4; ++n)
                acc[4 + m][n] = MFMA_BF16(av[m], bv0[n], acc[4 + m][n], 0, 0, 0);
        __builtin_amdgcn_s_setprio(0);
        __builtin_amdgcn_s_barrier();

        // phase 3: k1, mf0-3
#pragma unroll
        for (int m = 0; m < 4; ++m) av[m]  = *(const short8*)(Ak1 + m * 512);
#pragma unroll
        for (int n = 0; n < 4; ++n) bv1[n] = *(const short8*)(Bk1 + n * 512);
        if (t + 2 < nt) {
            const int ko = (t + 2) * 64;
            GLD(sA0 + ko, &L[LIDX(cur, 0, 0, 0) + dst8]);
            GLD(sA1 + ko, &L[LIDX(cur, 0, 1, 0) + dst8]);
        }
        __builtin_amdgcn_s_barrier();
        asm volatile("s_waitcnt lgkmcnt(0)" ::: "memory");
        __builtin_amdgcn_sched_barrier(0);
        __builtin_amdgcn_s_setprio(1);
#pragma unroll
        for (int m = 0; m < 4; ++m)
#pragma unroll
            for (int n = 0; n < 4; ++n)
                acc[m][n] = MFMA_BF16(av[m], bv1[n], acc[m][n], 0, 0, 0);
        __builtin_amdgcn_s_setprio(0);
        __builtin_amdgcn_s_barrier();

        // phase 4: k1, mf4-7
#pragma unroll
        for (int m = 0; m < 4; ++m) av[m] = *(const short8*)(Ak1 + (4 + m) * 512);
        if (t + 2 < nt) {
            const int ko = (t + 2) * 64;
            GLD(sB0 + ko, &L[LIDX(cur, 1, 0, 0) + dst8]);
            GLD(sB1 + ko, &L[LIDX(cur, 1, 1, 0) + dst8]);
        }
        if (t + 1 < nt) {
            if (t + 2 < nt) { asm volatile("s_waitcnt vmcnt(8)" ::: "memory"); }
            else            { asm volatile("s_waitcnt vmcnt(4)" ::: "memory"); }
        }
        __builtin_amdgcn_s_barrier();
        asm volatile("s_waitcnt lgkmcnt(0)" ::: "memory");
        __builtin_amdgcn_sched_barrier(0);
        __builtin_amdgcn_s_setprio(1);
#pragma unroll
        for (int m = 0; m < 4; ++m)
#pragma unroll
            for (int n = 0; n < 4; ++n)
                acc[4 + m][n] = MFMA_BF16(av[m], bv1[n], acc[4 + m][n], 0, 0, 0);
        __builtin_amdgcn_s_setprio(0);
        __builtin_amdgcn_s_barrier();
    }
}

// QK projection on the 8-phase core: grid 256 x 512thr.
__global__ __launch_bounds__(512, 2) void qk_gemm256(const unsigned short* __restrict__ xb,
                                                     const unsigned short* __restrict__ wb,
                                                     unsigned short* __restrict__ Qb,
                                                     unsigned short* __restrict__ Kb) {
    __shared__ __align__(16) unsigned short L[16 * 4096];
    const int lane = threadIdx.x & 63, wave = threadIdx.x >> 6;
    const int wm = wave >> 2, wn = wave & 3;
    const int lo = lane & 15, hi = lane >> 4;

    const int wg  = (blockIdx.x & 7) * 32 + (blockIdx.x >> 3);
    const int bmA = wg >> 3;
    const int bnB = wg & 7;

    f32x4 acc[8][4] = {};
    core256(xb, wb, bmA, bnB, L, acc);

    unsigned short* O = (bnB < 4) ? Qb : Kb;
    const int rb = bmA * 256 + wm * 128 + hi * 4;
    const int cb = (bnB & 3) * 256 + wn * 64 + lo;
#pragma unroll
    for (int mf = 0; mf < 8; ++mf)
#pragma unroll
        for (int nf = 0; nf < 4; ++nf)
#pragma unroll
            for (int r = 0; r < 4; ++r)
                O[(size_t)(rb + mf * 16 + r) * D_DIM + (cb + nf * 16)] = f2bf(acc[mf][nf][r]);
}

// S scores on the 8-phase core: grid 144 = 36 causal 256-tiles x 4 batches.
__global__ __launch_bounds__(512, 2) void s_gemm256(const unsigned short* __restrict__ Qb,
                                                    const unsigned short* __restrict__ Kb,
                                                    float* __restrict__ S) {
    __shared__ __align__(16) unsigned short L[16 * 4096];
    const int lane = threadIdx.x & 63, wave = threadIdx.x >> 6;
    const int wm = wave >> 2, wn = wave & 3;
    const int lo = lane & 15, hi = lane >> 4;

    const int wg = (blockIdx.x & 7) * 18 + (blockIdx.x >> 3);
    const int z  = wg / 36;
    int i = wg % 36;
    int bm = 0;
    while (i >= bm + 1) { i -= (bm + 1); ++bm; }
    const int bn = i;

    const unsigned short* Ap = Qb + (size_t)z * T_SEQ * D_DIM;
    const unsigned short* Bp = Kb + (size_t)z * T_SEQ * D_DIM;
    f32x4 acc[8][4] = {};
    core256(Ap, Bp, bm, bn, L, acc);

    float* Sp = S + (size_t)z * T_SEQ * T_SEQ;
    const float scale = 0.03125f;
    const int rb = bm * 256 + wm * 128 + hi * 4;
    const int cb = bn * 256 + wn * 64 + lo;
#pragma unroll
    for (int mf = 0; mf < 8; ++mf)
#pragma unroll
        for (int nf = 0; nf < 4; ++nf)
#pragma unroll
            for (int r = 0; r < 4; ++r) {
                const int row = rb + mf * 16 + r;
                const int col = cb + nf * 16;
                if (col <= row) Sp[(size_t)row * T_SEQ + col] = acc[mf][nf][r] * scale;
            }
}

// ---------------------------------------------------------------------------
// 128x128 core (r4-PROVEN, reverted): depth-2 prefetch over 3 buffers,
// counted vmcnt, 2 barriers/K-step, T2 swizzle.  Used by v_gemm / pv_gemm.
// ---------------------------------------------------------------------------
__device__ __forceinline__ void gemm_core(const unsigned short* __restrict__ A,
                                          const unsigned short* __restrict__ B,
                                          int lda, int ldb, int bm, int bn, int kend,
                                          f32x4 acc[4][4]) {
    __shared__ __align__(16) unsigned short As[3][128 * 32];
    __shared__ __align__(16) unsigned short Bs[3][128 * 32];
    const int tid  = threadIdx.x;
    const int lane = tid & 63;
    const int wave = tid >> 6;
    const int wm   = (wave >> 1) * 64;
    const int wn   = (wave & 1) * 64;
    const int lo   = lane & 15;
    const int hi   = lane >> 4;
    const int r0   = tid >> 2;
    const int q0   = (((tid & 3) ^ ((r0 >> 1) & 3)) * 8);

    const unsigned short* Arow0 = A + (size_t)(bm * 128 + r0) * lda + q0;
    const unsigned short* Arow1 = A + (size_t)(bm * 128 + r0 + 64) * lda + q0;
    const unsigned short* Brow0 = B + (size_t)(bn * 128 + r0) * ldb + q0;
    const unsigned short* Brow1 = B + (size_t)(bn * 128 + r0 + 64) * ldb + q0;

#define STAGE(t, buf) do { const int kk_ = (t) << 5; \
        GLD(Arow0 + kk_, As[buf] + tid * 8); \
        GLD(Arow1 + kk_, As[buf] + (tid + 256) * 8); \
        GLD(Brow0 + kk_, Bs[buf] + tid * 8); \
        GLD(Brow1 + kk_, Bs[buf] + (tid + 256) * 8); } while (0)

    const int nt = kend >> 5;
    STAGE(0, 0);
    STAGE(1, 1);

    int aoff[4], boff[4];
#pragma unroll
    for (int m = 0; m < 4; ++m) {
        const int ra = wm + m * 16 + lo;
        const int rb = wn + m * 16 + lo;
        aoff[m] = ra * 32 + ((hi ^ ((ra >> 1) & 3)) * 8);
        boff[m] = rb * 32 + ((hi ^ ((rb >> 1) & 3)) * 8);
    }

    int cur = 0;
    for (int t = 0; t < nt; ++t) {
        __builtin_amdgcn_s_barrier();
        if (t + 2 < nt) {
            int nb = cur + 2; if (nb >= 3) nb -= 3;
            STAGE(t + 2, nb);
            asm volatile("s_waitcnt vmcnt(8)" ::: "memory");
        } else if (t + 1 < nt) {
            asm volatile("s_waitcnt vmcnt(4)" ::: "memory");
        } else {
            asm volatile("s_waitcnt vmcnt(0)" ::: "memory");
        }
        __builtin_amdgcn_s_barrier();
        __builtin_amdgcn_sched_barrier(0);

        short8 av[4], bv[4];
#pragma unroll
        for (int m = 0; m < 4; ++m) av[m] = *(const short8*)&As[cur][aoff[m]];
#pragma unroll
        for (int n = 0; n < 4; ++n) bv[n] = *(const short8*)&Bs[cur][boff[n]];
        asm volatile("s_waitcnt lgkmcnt(0)" ::: "memory");
        __builtin_amdgcn_sched_barrier(0);

        __builtin_amdgcn_s_setprio(1);
#pragma unroll
        for (int m = 0; m < 4; ++m)
#pragma unroll
            for (int n = 0; n < 4; ++n)
                acc[m][n] = MFMA_BF16(av[m], bv[n], acc[m][n], 0, 0, 0);
        __builtin_amdgcn_s_setprio(0);

        cur += 1; if (cur >= 3) cur = 0;
    }
#undef STAGE
}

// V^T via operand swap: C[e][t] = sum_d Wv[e][d] x[t][d]; grid (64 t-blocks, 8 e-blocks).
__global__ __launch_bounds__(256) void v_gemm(const unsigned short* __restrict__ xb,
                                              const unsigned short* __restrict__ wv,
                                              unsigned short* __restrict__ Vt) {
    const int lane = threadIdx.x & 63, wave = threadIdx.x >> 6;
    f32x4 acc[4][4] = {};
    gemm_core(wv, xb, D_DIM, D_DIM, blockIdx.y, blockIdx.x, D_DIM, acc);
    const int rb = blockIdx.y * 128 + (wave >> 1) * 64 + ((lane >> 4) << 2);   // e
    const int cb = blockIdx.x * 128 + (wave & 1) * 64 + (lane & 15);           // t global
#pragma unroll
    for (int m = 0; m < 4; ++m)
#pragma unroll
        for (int n = 0; n < 4; ++n)
#pragma unroll
            for (int r = 0; r < 4; ++r) {
                const int e = rb + m * 16 + r;
                const int t = cb + n * 16;
                Vt[((size_t)(t >> 11) * D_DIM + e) * T_SEQ + (t & 2047)] = f2bf(acc[m][n][r]);
            }
}

// Wave-per-row softmax: 4 rows/block, row in registers, shuffle reductions.
__global__ __launch_bounds__(256) void softmax_kernel(const float* __restrict__ S,
                                                      unsigned short* __restrict__ P) {
    const int lane = threadIdx.x & 63, wave = threadIdx.x >> 6;
    const int row = blockIdx.x * 4 + wave;
    const int b = row >> 11, i = row & 2047;
    const float* srow = S + ((size_t)b * T_SEQ + i) * T_SEQ;
    unsigned short* prow = P + ((size_t)b * T_SEQ + i) * T_SEQ;
    const int len = i + 1;
    const int padlen = ((i >> 7) + 1) * 128;

    f32x4 v[8];
    float m = -1e30f;
#pragma unroll
    for (int c = 0; c < 8; ++c) {
        const int j0 = (c * 64 + lane) * 4;
        if (j0 < padlen) {
            v[c] = *(const f32x4*)(srow + j0);
#pragma unroll
            for (int e = 0; e < 4; ++e)
                if (j0 + e < len) m = fmaxf(m, v[c][e]);
        }
    }
#pragma unroll
    for (int off = 32; off; off >>= 1) m = fmaxf(m, __shfl_xor(m, off, 64));

    float s = 0.f;
#pragma unroll
    for (int c = 0; c < 8; ++c) {
        const int j0 = (c * 64 + lane) * 4;
        if (j0 < padlen) {
#pragma unroll
            for (int e = 0; e < 4; ++e) {
                float ev = (j0 + e < len) ? __expf(v[c][e] - m) : 0.f;
                v[c][e] = ev;
                s += ev;
            }
        }
    }
#pragma unroll
    for (int off = 32; off; off >>= 1) s += __shfl_xor(s, off, 64);
    const float inv = 1.f / s;

#pragma unroll
    for (int c = 0; c < 8; ++c) {
        const int j0 = (c * 64 + lane) * 4;
        if (j0 < padlen) {
            ushort4 o;
            o.x = f2bf(v[c][0] * inv);
            o.y = f2bf(v[c][1] * inv);
            o.z = f2bf(v[c][2] * inv);
            o.w = f2bf(v[c][3] * inv);
            *(ushort4*)(prow + j0) = o;
        }
    }
}

// Flat grid of 512, ANTITHETIC PAIRING: HW co-schedules blocks d and d+256 on
// the same CU (8-XCD round-robin by d%8, 64 blocks/XCD over 32 CUs).  Decode
// gives them bm = 15-k and k, so every CU-pair sums to exactly 68 K-steps
// (perfect balance; r9's decode paired 15 with 11 -> 112-step straggler CUs).
// z = d&3 is constant per XCD -> Vt[z] (4 MB) stays L2-hot.
__global__ __launch_bounds__(256) void pv_gemm(const unsigned short* __restrict__ P,
                                               const unsigned short* __restrict__ Vt,
                                               float* __restrict__ Out) {
    const int d = blockIdx.x;
    const int u = d & 255;
    const int k = u >> 5;                       // 0..7
    const int bm = (d < 256) ? (15 - k) : k;    // pair sums = 15
    const int bn = (u >> 2) & 7;
    const int z  = u & 3;

    const unsigned short* Ap = P + (size_t)z * T_SEQ * T_SEQ;
    const unsigned short* Bp = Vt + (size_t)z * D_DIM * T_SEQ;
    f32x4 acc[4][4] = {};
    gemm_core(Ap, Bp, T_SEQ, T_SEQ, bm, bn, (bm + 1) * 128, acc);

    float* Op = Out + (size_t)z * T_SEQ * D_DIM;
    const int lane = threadIdx.x & 63, wave = threadIdx.x >> 6;
    const int rb = bm * 128 + (wave >> 1) * 64 + ((lane >> 4) << 2);
    const int cb = bn * 128 + (wave & 1) * 64 + (lane & 15);
#pragma unroll
    for (int m = 0; m < 4; ++m)
#pragma unroll
        for (int n = 0; n < 4; ++n)
#pragma unroll
            for (int r = 0; r < 4; ++r)
                Op[(size_t)(rb + m * 16 + r) * D_DIM + (cb + n * 16)] = acc[m][n][r];
}

extern "C" void kernel_launch(void* const* d_in, const int* in_sizes, int n_in,
                              void* d_out, int out_size, void* d_ws, size_t ws_size,
                              hipStream_t stream) {
    const float* x  = (const float*)d_in[0];
    const float* Wq = (const float*)d_in[1];
    const float* Wk = (const float*)d_in[2];
    const float* Wv = (const float*)d_in[3];
    float* out = (float*)d_out;
    char* ws = (char*)d_ws;

    unsigned short* xb = (unsigned short*)(ws);                 // 16 MB  x bf16 [8192,1024]
    unsigned short* wb = (unsigned short*)(ws + 16777216);      // 6 MB   Wq|Wk|Wv bf16
    unsigned short* Qb = (unsigned short*)(ws + 23068672);      // 16 MB
    unsigned short* Kb = (unsigned short*)(ws + 39845888);      // 16 MB
    unsigned short* Vt = (unsigned short*)(ws + 56623104);      // 16 MB  V^T per batch [1024][2048]
    float*          S  = (float*)(ws + 73400320);               // 64 MB  scores fp32
    unsigned short* P  = (unsigned short*)(ws + 140509184);     // 32 MB  probs bf16
    (void)ws_size; (void)in_sizes; (void)n_in; (void)out_size;

    cast_kernel<<<8192, 256, 0, stream>>>((const float4*)x, (ushort4*)xb, 2097152);
    cast3_kernel<<<3072, 256, 0, stream>>>((const float4*)Wq, (const float4*)Wk,
                                           (const float4*)Wv, (ushort4*)wb);

    qk_gemm256<<<256, 512, 0, stream>>>(xb, wb, Qb, Kb);
    v_gemm<<<dim3(64, 8), 256, 0, stream>>>(xb, wb + 2097152, Vt);
    s_gemm256<<<144, 512, 0, stream>>>(Qb, Kb, S);
    softmax_kernel<<<2048, 256, 0, stream>>>(S, P);
    pv_gemm<<<512, 256, 0, stream>>>(P, Vt, out);
}

// Round 12
// 158.231 us; speedup vs baseline: 1.1214x; 1.0319x over previous
//
#include <hip/hip_runtime.h>
#include <hip/hip_bf16.h>

#define T_SEQ 2048
#define D_DIM 1024
#define NB 4

typedef __attribute__((ext_vector_type(8))) short short8;
typedef __attribute__((ext_vector_type(4))) float f32x4;

__device__ __forceinline__ unsigned short f2bf(float f) {
    unsigned int u = __float_as_uint(f);
    u = (u + 0x7FFFu + ((u >> 16) & 1u)) >> 16;
    return (unsigned short)u;
}

// One launch: x (blocks 0..8191) then Wq|Wk|Wv (blocks 8192..11263).
__global__ void cast_all(const float4* __restrict__ x, const float4* __restrict__ wq,
                         const float4* __restrict__ wk, const float4* __restrict__ wv,
                         ushort4* __restrict__ xb, ushort4* __restrict__ wb) {
    const int b = blockIdx.x;
    float4 f;
    ushort4* dst;
    if (b < 8192) {
        const int i = b * 256 + threadIdx.x;
        f = x[i];
        dst = xb + i;
    } else {
        const int i = (b - 8192) * 256 + threadIdx.x;   // < 786432
        const int w = i >> 18;                          // /262144
        const int j = i & 262143;
        const float4* src = (w == 0) ? wq : (w == 1) ? wk : wv;
        f = src[j];
        dst = wb + i;
    }
    ushort4 o;
    o.x = f2bf(f.x); o.y = f2bf(f.y); o.z = f2bf(f.z); o.w = f2bf(f.w);
    *dst = o;
}

#define GLD(gp, lp) __builtin_amdgcn_global_load_lds( \
    (__attribute__((address_space(1))) void*)(gp), \
    (__attribute__((address_space(3))) void*)(lp), 16, 0, 0)

#define MFMA_BF16 __builtin_amdgcn_mfma_f32_16x16x32_bf16

// ===========================================================================
// 8-phase 256x256 core (r7-proven, unchanged): used by qk_gemm256 / s_gemm256.
// ===========================================================================
#define LIDX(slot, ab, half, ks) ((((((slot)*2 + (ab))*2 + (half))*2 + (ks)) * 4096))

__device__ __forceinline__ void core256(const unsigned short* __restrict__ Ap,
                                        const unsigned short* __restrict__ Bp,
                                        int bmA, int bnB,
                                        unsigned short* __restrict__ L,
                                        f32x4 acc[8][4]) {
    const int tid  = threadIdx.x;
    const int lane = tid & 63;
    const int wave = tid >> 6;
    const int wm   = wave >> 2;
    const int wn   = wave & 3;
    const int bh   = wn >> 1;
    const int lo   = lane & 15;
    const int hi   = lane >> 4;

    const int srow   = tid >> 2;
    const int schoff = (((tid & 3) ^ ((srow >> 1) & 3)) << 3);
    const unsigned short* sA0 = Ap + (size_t)(bmA * 256 +       srow) * 1024 + schoff;
    const unsigned short* sA1 = Ap + (size_t)(bmA * 256 + 128 + srow) * 1024 + schoff;
    const unsigned short* sB0 = Bp + (size_t)(bnB * 256 +       srow) * 1024 + schoff;
    const unsigned short* sB1 = Bp + (size_t)(bnB * 256 + 128 + srow) * 1024 + schoff;
    const int dst8 = tid * 8;

    const int choff  = ((hi ^ ((lo >> 1) & 3)) << 3);
    const int alocal = lo * 32 + choff;
    const int blocal = ((wn & 1) * 64 + lo) * 32 + choff;

    GLD(sA0,       &L[LIDX(0,0,0,0) + dst8]);  GLD(sA1,       &L[LIDX(0,0,1,0) + dst8]);
    GLD(sB0,       &L[LIDX(0,1,0,0) + dst8]);  GLD(sB1,       &L[LIDX(0,1,1,0) + dst8]);
    GLD(sA0 + 32,  &L[LIDX(0,0,0,1) + dst8]);  GLD(sA1 + 32,  &L[LIDX(0,0,1,1) + dst8]);
    GLD(sB0 + 32,  &L[LIDX(0,1,0,1) + dst8]);  GLD(sB1 + 32,  &L[LIDX(0,1,1,1) + dst8]);
    GLD(sA0 + 64,  &L[LIDX(1,0,0,0) + dst8]);  GLD(sA1 + 64,  &L[LIDX(1,0,1,0) + dst8]);
    GLD(sB0 + 64,  &L[LIDX(1,1,0,0) + dst8]);  GLD(sB1 + 64,  &L[LIDX(1,1,1,0) + dst8]);
    asm volatile("s_waitcnt vmcnt(8)" ::: "memory");
    __builtin_amdgcn_s_barrier();

    const int nt = 16;
    for (int t = 0; t < nt; ++t) {
        const int cur = t & 1;
        const unsigned short* Ak0 = &L[LIDX(cur, 0, wm, 0)] + alocal;
        const unsigned short* Bk0 = &L[LIDX(cur, 1, bh, 0)] + blocal;
        const unsigned short* Ak1 = &L[LIDX(cur, 0, wm, 1)] + alocal;
        const unsigned short* Bk1 = &L[LIDX(cur, 1, bh, 1)] + blocal;
        short8 av[4], bv0[4], bv1[4];

        // phase 1: k0, mf0-3
#pragma unroll
        for (int m = 0; m < 4; ++m) av[m]  = *(const short8*)(Ak0 + m * 512);
#pragma unroll
        for (int n = 0; n < 4; ++n) bv0[n] = *(const short8*)(Bk0 + n * 512);
        if (t + 1 < nt) {
            const int ko = (t + 1) * 64 + 32;
            GLD(sA0 + ko, &L[LIDX(cur ^ 1, 0, 0, 1) + dst8]);
            GLD(sA1 + ko, &L[LIDX(cur ^ 1, 0, 1, 1) + dst8]);
        }
        __builtin_amdgcn_s_barrier();
        asm volatile("s_waitcnt lgkmcnt(0)" ::: "memory");
        __builtin_amdgcn_sched_barrier(0);
        __builtin_amdgcn_s_setprio(1);
#pragma unroll
        for (int m = 0; m < 4; ++m)
#pragma unroll
            for (int n = 0; n < 4; ++n)
                acc[m][n] = MFMA_BF16(av[m], bv0[n], acc[m][n], 0, 0, 0);
        __builtin_amdgcn_s_setprio(0);
        __builtin_amdgcn_s_barrier();

        // phase 2: k0, mf4-7
#pragma unroll
        for (int m = 0; m < 4; ++m) av[m] = *(const short8*)(Ak0 + (4 + m) * 512);
        if (t + 1 < nt) {
            const int ko = (t + 1) * 64 + 32;
            GLD(sB0 + ko, &L[LIDX(cur ^ 1, 1, 0, 1) + dst8]);
            GLD(sB1 + ko, &L[LIDX(cur ^ 1, 1, 1, 1) + dst8]);
        }
        if (t + 1 < nt) { asm volatile("s_waitcnt vmcnt(8)" ::: "memory"); }
        else            { asm volatile("s_waitcnt vmcnt(0)" ::: "memory"); }
        __builtin_amdgcn_s_barrier();
        asm volatile("s_waitcnt lgkmcnt(0)" ::: "memory");
        __builtin_amdgcn_sched_barrier(0);
        __builtin_amdgcn_s_setprio(1);
#pragma unroll
        for (int m = 0; m < 4; ++m)
#pragma unroll
            for (int n = 0; n < 4; ++n)
                acc[4 + m][n] = MFMA_BF16(av[m], bv0[n], acc[4 + m][n], 0, 0, 0);
        __builtin_amdgcn_s_setprio(0);
        __builtin_amdgcn_s_barrier();

        // phase 3: k1, mf0-3
#pragma unroll
        for (int m = 0; m < 4; ++m) av[m]  = *(const short8*)(Ak1 + m * 512);
#pragma unroll
        for (int n = 0; n < 4; ++n) bv1[n] = *(const short8*)(Bk1 + n * 512);
        if (t + 2 < nt) {
            const int ko = (t + 2) * 64;
            GLD(sA0 + ko, &L[LIDX(cur, 0, 0, 0) + dst8]);
            GLD(sA1 + ko, &L[LIDX(cur, 0, 1, 0) + dst8]);
        }
        __builtin_amdgcn_s_barrier();
        asm volatile("s_waitcnt lgkmcnt(0)" ::: "memory");
        __builtin_amdgcn_sched_barrier(0);
        __builtin_amdgcn_s_setprio(1);
#pragma unroll
        for (int m = 0; m < 4; ++m)
#pragma unroll
            for (int n = 0; n < 4; ++n)
                acc[m][n] = MFMA_BF16(av[m], bv1[n], acc[m][n], 0, 0, 0);
        __builtin_amdgcn_s_setprio(0);
        __builtin_amdgcn_s_barrier();

        // phase 4: k1, mf4-7
#pragma unroll
        for (int m = 0; m < 4; ++m) av[m] = *(const short8*)(Ak1 + (4 + m) * 512);
        if (t + 2 < nt) {
            const int ko = (t + 2) * 64;
            GLD(sB0 + ko, &L[LIDX(cur, 1, 0, 0) + dst8]);
            GLD(sB1 + ko, &L[LIDX(cur, 1, 1, 0) + dst8]);
        }
        if (t + 1 < nt) {
            if (t + 2 < nt) { asm volatile("s_waitcnt vmcnt(8)" ::: "memory"); }
            else            { asm volatile("s_waitcnt vmcnt(4)" ::: "memory"); }
        }
        __builtin_amdgcn_s_barrier();
        asm volatile("s_waitcnt lgkmcnt(0)" ::: "memory");
        __builtin_amdgcn_sched_barrier(0);
        __builtin_amdgcn_s_setprio(1);
#pragma unroll
        for (int m = 0; m < 4; ++m)
#pragma unroll
            for (int n = 0; n < 4; ++n)
                acc[4 + m][n] = MFMA_BF16(av[m], bv1[n], acc[4 + m][n], 0, 0, 0);
        __builtin_amdgcn_s_setprio(0);
        __builtin_amdgcn_s_barrier();
    }
}

// QK projection on the 8-phase core: grid 256 x 512thr.
__global__ __launch_bounds__(512, 2) void qk_gemm256(const unsigned short* __restrict__ xb,
                                                     const unsigned short* __restrict__ wb,
                                                     unsigned short* __restrict__ Qb,
                                                     unsigned short* __restrict__ Kb) {
    __shared__ __align__(16) unsigned short L[16 * 4096];
    const int lane = threadIdx.x & 63, wave = threadIdx.x >> 6;
    const int wm = wave >> 2, wn = wave & 3;
    const int lo = lane & 15, hi = lane >> 4;

    const int wg  = (blockIdx.x & 7) * 32 + (blockIdx.x >> 3);
    const int bmA = wg >> 3;
    const int bnB = wg & 7;

    f32x4 acc[8][4] = {};
    core256(xb, wb, bmA, bnB, L, acc);

    unsigned short* O = (bnB < 4) ? Qb : Kb;
    const int rb = bmA * 256 + wm * 128 + hi * 4;
    const int cb = (bnB & 3) * 256 + wn * 64 + lo;
#pragma unroll
    for (int mf = 0; mf < 8; ++mf)
#pragma unroll
        for (int nf = 0; nf < 4; ++nf)
#pragma unroll
            for (int r = 0; r < 4; ++r)
                O[(size_t)(rb + mf * 16 + r) * D_DIM + (cb + nf * 16)] = f2bf(acc[mf][nf][r]);
}

// S scores on the 8-phase core: grid 144 = 36 causal 256-tiles x 4 batches.
__global__ __launch_bounds__(512, 2) void s_gemm256(const unsigned short* __restrict__ Qb,
                                                    const unsigned short* __restrict__ Kb,
                                                    float* __restrict__ S) {
    __shared__ __align__(16) unsigned short L[16 * 4096];
    const int lane = threadIdx.x & 63, wave = threadIdx.x >> 6;
    const int wm = wave >> 2, wn = wave & 3;
    const int lo = lane & 15, hi = lane >> 4;

    const int wg = (blockIdx.x & 7) * 18 + (blockIdx.x >> 3);
    const int z  = wg / 36;
    int i = wg % 36;
    int bm = 0;
    while (i >= bm + 1) { i -= (bm + 1); ++bm; }
    const int bn = i;

    const unsigned short* Ap = Qb + (size_t)z * T_SEQ * D_DIM;
    const unsigned short* Bp = Kb + (size_t)z * T_SEQ * D_DIM;
    f32x4 acc[8][4] = {};
    core256(Ap, Bp, bm, bn, L, acc);

    float* Sp = S + (size_t)z * T_SEQ * T_SEQ;
    const float scale = 0.03125f;
    const int rb = bm * 256 + wm * 128 + hi * 4;
    const int cb = bn * 256 + wn * 64 + lo;
#pragma unroll
    for (int mf = 0; mf < 8; ++mf)
#pragma unroll
        for (int nf = 0; nf < 4; ++nf)
#pragma unroll
            for (int r = 0; r < 4; ++r) {
                const int row = rb + mf * 16 + r;
                const int col = cb + nf * 16;
                if (col <= row) Sp[(size_t)row * T_SEQ + col] = acc[mf][nf][r] * scale;
            }
}

// ---------------------------------------------------------------------------
// 128x128 core (r4-proven): depth-2 prefetch over 3 buffers, counted vmcnt,
// 2 barriers/K-step, T2 swizzle.  Used by v_gemm / pv_gemm.
// ---------------------------------------------------------------------------
__device__ __forceinline__ void gemm_core(const unsigned short* __restrict__ A,
                                          const unsigned short* __restrict__ B,
                                          int lda, int ldb, int bm, int bn, int kend,
                                          f32x4 acc[4][4]) {
    __shared__ __align__(16) unsigned short As[3][128 * 32];
    __shared__ __align__(16) unsigned short Bs[3][128 * 32];
    const int tid  = threadIdx.x;
    const int lane = tid & 63;
    const int wave = tid >> 6;
    const int wm   = (wave >> 1) * 64;
    const int wn   = (wave & 1) * 64;
    const int lo   = lane & 15;
    const int hi   = lane >> 4;
    const int r0   = tid >> 2;
    const int q0   = (((tid & 3) ^ ((r0 >> 1) & 3)) * 8);

    const unsigned short* Arow0 = A + (size_t)(bm * 128 + r0) * lda + q0;
    const unsigned short* Arow1 = A + (size_t)(bm * 128 + r0 + 64) * lda + q0;
    const unsigned short* Brow0 = B + (size_t)(bn * 128 + r0) * ldb + q0;
    const unsigned short* Brow1 = B + (size_t)(bn * 128 + r0 + 64) * ldb + q0;

#define STAGE(t, buf) do { const int kk_ = (t) << 5; \
        GLD(Arow0 + kk_, As[buf] + tid * 8); \
        GLD(Arow1 + kk_, As[buf] + (tid + 256) * 8); \
        GLD(Brow0 + kk_, Bs[buf] + tid * 8); \
        GLD(Brow1 + kk_, Bs[buf] + (tid + 256) * 8); } while (0)

    const int nt = kend >> 5;
    STAGE(0, 0);
    STAGE(1, 1);

    int aoff[4], boff[4];
#pragma unroll
    for (int m = 0; m < 4; ++m) {
        const int ra = wm + m * 16 + lo;
        const int rb = wn + m * 16 + lo;
        aoff[m] = ra * 32 + ((hi ^ ((ra >> 1) & 3)) * 8);
        boff[m] = rb * 32 + ((hi ^ ((rb >> 1) & 3)) * 8);
    }

    int cur = 0;
    for (int t = 0; t < nt; ++t) {
        __builtin_amdgcn_s_barrier();
        if (t + 2 < nt) {
            int nb = cur + 2; if (nb >= 3) nb -= 3;
            STAGE(t + 2, nb);
            asm volatile("s_waitcnt vmcnt(8)" ::: "memory");
        } else if (t + 1 < nt) {
            asm volatile("s_waitcnt vmcnt(4)" ::: "memory");
        } else {
            asm volatile("s_waitcnt vmcnt(0)" ::: "memory");
        }
        __builtin_amdgcn_s_barrier();
        __builtin_amdgcn_sched_barrier(0);

        short8 av[4], bv[4];
#pragma unroll
        for (int m = 0; m < 4; ++m) av[m] = *(const short8*)&As[cur][aoff[m]];
#pragma unroll
        for (int n = 0; n < 4; ++n) bv[n] = *(const short8*)&Bs[cur][boff[n]];
        asm volatile("s_waitcnt lgkmcnt(0)" ::: "memory");
        __builtin_amdgcn_sched_barrier(0);

        __builtin_amdgcn_s_setprio(1);
#pragma unroll
        for (int m = 0; m < 4; ++m)
#pragma unroll
            for (int n = 0; n < 4; ++n)
                acc[m][n] = MFMA_BF16(av[m], bv[n], acc[m][n], 0, 0, 0);
        __builtin_amdgcn_s_setprio(0);

        cur += 1; if (cur >= 3) cur = 0;
    }
#undef STAGE
}

// V^T via operand swap: C[e][t] = sum_d Wv[e][d] x[t][d]; grid (64 t-blocks, 8 e-blocks).
__global__ __launch_bounds__(256) void v_gemm(const unsigned short* __restrict__ xb,
                                              const unsigned short* __restrict__ wv,
                                              unsigned short* __restrict__ Vt) {
    const int lane = threadIdx.x & 63, wave = threadIdx.x >> 6;
    f32x4 acc[4][4] = {};
    gemm_core(wv, xb, D_DIM, D_DIM, blockIdx.y, blockIdx.x, D_DIM, acc);
    const int rb = blockIdx.y * 128 + (wave >> 1) * 64 + ((lane >> 4) << 2);   // e
    const int cb = blockIdx.x * 128 + (wave & 1) * 64 + (lane & 15);           // t global
#pragma unroll
    for (int m = 0; m < 4; ++m)
#pragma unroll
        for (int n = 0; n < 4; ++n)
#pragma unroll
            for (int r = 0; r < 4; ++r) {
                const int e = rb + m * 16 + r;
                const int t = cb + n * 16;
                Vt[((size_t)(t >> 11) * D_DIM + e) * T_SEQ + (t & 2047)] = f2bf(acc[m][n][r]);
            }
}

// Wave-per-row softmax: 4 rows/block, row in registers, shuffle reductions.
__global__ __launch_bounds__(256) void softmax_kernel(const float* __restrict__ S,
                                                      unsigned short* __restrict__ P) {
    const int lane = threadIdx.x & 63, wave = threadIdx.x >> 6;
    const int row = blockIdx.x * 4 + wave;
    const int b = row >> 11, i = row & 2047;
    const float* srow = S + ((size_t)b * T_SEQ + i) * T_SEQ;
    unsigned short* prow = P + ((size_t)b * T_SEQ + i) * T_SEQ;
    const int len = i + 1;
    const int padlen = ((i >> 7) + 1) * 128;

    f32x4 v[8];
    float m = -1e30f;
#pragma unroll
    for (int c = 0; c < 8; ++c) {
        const int j0 = (c * 64 + lane) * 4;
        if (j0 < padlen) {
            v[c] = *(const f32x4*)(srow + j0);
#pragma unroll
            for (int e = 0; e < 4; ++e)
                if (j0 + e < len) m = fmaxf(m, v[c][e]);
        }
    }
#pragma unroll
    for (int off = 32; off; off >>= 1) m = fmaxf(m, __shfl_xor(m, off, 64));

    float s = 0.f;
#pragma unroll
    for (int c = 0; c < 8; ++c) {
        const int j0 = (c * 64 + lane) * 4;
        if (j0 < padlen) {
#pragma unroll
            for (int e = 0; e < 4; ++e) {
                float ev = (j0 + e < len) ? __expf(v[c][e] - m) : 0.f;
                v[c][e] = ev;
                s += ev;
            }
        }
    }
#pragma unroll
    for (int off = 32; off; off >>= 1) s += __shfl_xor(s, off, 64);
    const float inv = 1.f / s;

#pragma unroll
    for (int c = 0; c < 8; ++c) {
        const int j0 = (c * 64 + lane) * 4;
        if (j0 < padlen) {
            ushort4 o;
            o.x = f2bf(v[c][0] * inv);
            o.y = f2bf(v[c][1] * inv);
            o.z = f2bf(v[c][2] * inv);
            o.w = f2bf(v[c][3] * inv);
            *(ushort4*)(prow + j0) = o;
        }
    }
}

// ===========================================================================
// pv split-K: 768 blocks, EVERY co-scheduled triple (d, d+256, d+512) sums to
// exactly 68 K-steps -> balanced AND 3 streams/CU throughout.
//   cat0 (d<256):   bm=7-k, whole K          (32-4k steps) -> Out
//   cat1 (d<512):   bm=8+k, K-half [0,h)     (18+2k steps) -> Out (partial)
//   cat2 (d<768):   bm=8+k, K-half [h,2h)    (18+2k steps) -> Ppart scratch
// (k = (d&255)>>5, h=(bm+1)*64.)  pv_reduce then does Out += Ppart for the
// split rows (1024..2047 per batch).  Ppart reuses the S buffer (dead after
// softmax).  Sum order change vs r11: two fp32 chains + one add; absmax may
// move +-ulp.
// ===========================================================================
__global__ __launch_bounds__(256) void pv_gemm(const unsigned short* __restrict__ P,
                                               const unsigned short* __restrict__ Vt,
                                               float* __restrict__ Out,
                                               float* __restrict__ Ppart) {
    const int d = blockIdx.x;
    const int u = d & 255;
    const int k = u >> 5;                 // 0..7
    const int bn = (u >> 2) & 7;
    const int z  = u & 3;
    const int cat = d >> 8;               // 0,1,2

    int bm, kstart, klen;
    if (cat == 0) { bm = 7 - k;  kstart = 0;              klen = (bm + 1) * 128; }
    else          { bm = 8 + k;  const int h = (bm + 1) * 64;
                    kstart = (cat == 2) ? h : 0;          klen = h; }

    const unsigned short* Ap = P  + (size_t)z * T_SEQ * T_SEQ + kstart;
    const unsigned short* Bp = Vt + (size_t)z * D_DIM * T_SEQ + kstart;
    f32x4 acc[4][4] = {};
    gemm_core(Ap, Bp, T_SEQ, T_SEQ, bm, bn, klen, acc);

    const int lane = threadIdx.x & 63, wave = threadIdx.x >> 6;
    const int rb = bm * 128 + (wave >> 1) * 64 + ((lane >> 4) << 2);
    const int cb = bn * 128 + (wave & 1) * 64 + (lane & 15);
    if (cat < 2) {
        float* Op = Out + (size_t)z * T_SEQ * D_DIM;
#pragma unroll
        for (int m = 0; m < 4; ++m)
#pragma unroll
            for (int n = 0; n < 4; ++n)
#pragma unroll
                for (int r = 0; r < 4; ++r)
                    Op[(size_t)(rb + m * 16 + r) * D_DIM + (cb + n * 16)] = acc[m][n][r];
    } else {
        // partial for rows 1024..2047 of batch z -> Ppart[z][row-1024][col]
        float* Pp = Ppart + (size_t)z * 1024 * D_DIM;
#pragma unroll
        for (int m = 0; m < 4; ++m)
#pragma unroll
            for (int n = 0; n < 4; ++n)
#pragma unroll
                for (int r = 0; r < 4; ++r)
                    Pp[(size_t)(rb - 1024 + m * 16 + r) * D_DIM + (cb + n * 16)] = acc[m][n][r];
    }
}

// Out rows 1024..2047 (per batch) += Ppart.  4M floats = 1M float4.
__global__ __launch_bounds__(256) void pv_reduce(float* __restrict__ Out,
                                                 const float* __restrict__ Ppart) {
    const int i = blockIdx.x * 256 + threadIdx.x;     // < 1048576 float4
    const int pf = i * 4;
    const int z = pf >> 20;                           // / (1024*1024)
    const int r = (pf >> 10) & 1023;
    const int c = pf & 1023;
    f32x4 a = *(const f32x4*)(Ppart + (size_t)pf);
    float* op = Out + ((size_t)z * 2048 + 1024 + r) * 1024 + c;
    f32x4 b = *(const f32x4*)op;
    b[0] += a[0]; b[1] += a[1]; b[2] += a[2]; b[3] += a[3];
    *(f32x4*)op = b;
}

extern "C" void kernel_launch(void* const* d_in, const int* in_sizes, int n_in,
                              void* d_out, int out_size, void* d_ws, size_t ws_size,
                              hipStream_t stream) {
    const float* x  = (const float*)d_in[0];
    const float* Wq = (const float*)d_in[1];
    const float* Wk = (const float*)d_in[2];
    const float* Wv = (const float*)d_in[3];
    float* out = (float*)d_out;
    char* ws = (char*)d_ws;

    unsigned short* xb = (unsigned short*)(ws);                 // 16 MB  x bf16 [8192,1024]
    unsigned short* wb = (unsigned short*)(ws + 16777216);      // 6 MB   Wq|Wk|Wv bf16
    unsigned short* Qb = (unsigned short*)(ws + 23068672);      // 16 MB
    unsigned short* Kb = (unsigned short*)(ws + 39845888);      // 16 MB
    unsigned short* Vt = (unsigned short*)(ws + 56623104);      // 16 MB  V^T per batch [1024][2048]
    float*          S  = (float*)(ws + 73400320);               // 64 MB  scores fp32
    unsigned short* P  = (unsigned short*)(ws + 140509184);     // 32 MB  probs bf16
    float*       Ppart = S;                                     // 16 MB  (S dead after softmax)
    (void)ws_size; (void)in_sizes; (void)n_in; (void)out_size;

    cast_all<<<11264, 256, 0, stream>>>((const float4*)x, (const float4*)Wq,
                                        (const float4*)Wk, (const float4*)Wv,
                                        (ushort4*)xb, (ushort4*)wb);

    qk_gemm256<<<256, 512, 0, stream>>>(xb, wb, Qb, Kb);
    v_gemm<<<dim3(64, 8), 256, 0, stream>>>(xb, wb + 2097152, Vt);
    s_gemm256<<<144, 512, 0, stream>>>(Qb, Kb, S);
    softmax_kernel<<<2048, 256, 0, stream>>>(S, P);
    pv_gemm<<<768, 256, 0, stream>>>(P, Vt, out, Ppart);
    pv_reduce<<<4096, 256, 0, stream>>>(out, Ppart);
}

// Round 13
// 152.399 us; speedup vs baseline: 1.1643x; 1.0383x over previous
//
#include <hip/hip_runtime.h>
#include <hip/hip_bf16.h>

#define T_SEQ 2048
#define D_DIM 1024
#define NB 4

typedef __attribute__((ext_vector_type(8))) short short8;
typedef __attribute__((ext_vector_type(4))) float f32x4;

__device__ __forceinline__ unsigned short f2bf(float f) {
    unsigned int u = __float_as_uint(f);
    u = (u + 0x7FFFu + ((u >> 16) & 1u)) >> 16;
    return (unsigned short)u;
}
__device__ __forceinline__ float bf2f(unsigned short h) {
    return __uint_as_float(((unsigned int)h) << 16);
}

// One launch: x (blocks 0..8191) then Wq|Wk|Wv (blocks 8192..11263).
__global__ void cast_all(const float4* __restrict__ x, const float4* __restrict__ wq,
                         const float4* __restrict__ wk, const float4* __restrict__ wv,
                         ushort4* __restrict__ xb, ushort4* __restrict__ wb) {
    const int b = blockIdx.x;
    float4 f;
    ushort4* dst;
    if (b < 8192) {
        const int i = b * 256 + threadIdx.x;
        f = x[i];
        dst = xb + i;
    } else {
        const int i = (b - 8192) * 256 + threadIdx.x;   // < 786432
        const int w = i >> 18;
        const int j = i & 262143;
        const float4* src = (w == 0) ? wq : (w == 1) ? wk : wv;
        f = src[j];
        dst = wb + i;
    }
    ushort4 o;
    o.x = f2bf(f.x); o.y = f2bf(f.y); o.z = f2bf(f.z); o.w = f2bf(f.w);
    *dst = o;
}

#define GLD(gp, lp) __builtin_amdgcn_global_load_lds( \
    (__attribute__((address_space(1))) void*)(gp), \
    (__attribute__((address_space(3))) void*)(lp), 16, 0, 0)

#define MFMA_BF16 __builtin_amdgcn_mfma_f32_16x16x32_bf16

// ===========================================================================
// 8-phase 256x256 core (r7-proven, unchanged): used by qk_gemm256 / s_gemm256.
// ===========================================================================
#define LIDX(slot, ab, half, ks) ((((((slot)*2 + (ab))*2 + (half))*2 + (ks)) * 4096))

__device__ __forceinline__ void core256(const unsigned short* __restrict__ Ap,
                                        const unsigned short* __restrict__ Bp,
                                        int bmA, int bnB,
                                        unsigned short* __restrict__ L,
                                        f32x4 acc[8][4]) {
    const int tid  = threadIdx.x;
    const int lane = tid & 63;
    const int wave = tid >> 6;
    const int wm   = wave >> 2;
    const int wn   = wave & 3;
    const int bh   = wn >> 1;
    const int lo   = lane & 15;
    const int hi   = lane >> 4;

    const int srow   = tid >> 2;
    const int schoff = (((tid & 3) ^ ((srow >> 1) & 3)) << 3);
    const unsigned short* sA0 = Ap + (size_t)(bmA * 256 +       srow) * 1024 + schoff;
    const unsigned short* sA1 = Ap + (size_t)(bmA * 256 + 128 + srow) * 1024 + schoff;
    const unsigned short* sB0 = Bp + (size_t)(bnB * 256 +       srow) * 1024 + schoff;
    const unsigned short* sB1 = Bp + (size_t)(bnB * 256 + 128 + srow) * 1024 + schoff;
    const int dst8 = tid * 8;

    const int choff  = ((hi ^ ((lo >> 1) & 3)) << 3);
    const int alocal = lo * 32 + choff;
    const int blocal = ((wn & 1) * 64 + lo) * 32 + choff;

    GLD(sA0,       &L[LIDX(0,0,0,0) + dst8]);  GLD(sA1,       &L[LIDX(0,0,1,0) + dst8]);
    GLD(sB0,       &L[LIDX(0,1,0,0) + dst8]);  GLD(sB1,       &L[LIDX(0,1,1,0) + dst8]);
    GLD(sA0 + 32,  &L[LIDX(0,0,0,1) + dst8]);  GLD(sA1 + 32,  &L[LIDX(0,0,1,1) + dst8]);
    GLD(sB0 + 32,  &L[LIDX(0,1,0,1) + dst8]);  GLD(sB1 + 32,  &L[LIDX(0,1,1,1) + dst8]);
    GLD(sA0 + 64,  &L[LIDX(1,0,0,0) + dst8]);  GLD(sA1 + 64,  &L[LIDX(1,0,1,0) + dst8]);
    GLD(sB0 + 64,  &L[LIDX(1,1,0,0) + dst8]);  GLD(sB1 + 64,  &L[LIDX(1,1,1,0) + dst8]);
    asm volatile("s_waitcnt vmcnt(8)" ::: "memory");
    __builtin_amdgcn_s_barrier();

    const int nt = 16;
    for (int t = 0; t < nt; ++t) {
        const int cur = t & 1;
        const unsigned short* Ak0 = &L[LIDX(cur, 0, wm, 0)] + alocal;
        const unsigned short* Bk0 = &L[LIDX(cur, 1, bh, 0)] + blocal;
        const unsigned short* Ak1 = &L[LIDX(cur, 0, wm, 1)] + alocal;
        const unsigned short* Bk1 = &L[LIDX(cur, 1, bh, 1)] + blocal;
        short8 av[4], bv0[4], bv1[4];

        // phase 1: k0, mf0-3
#pragma unroll
        for (int m = 0; m < 4; ++m) av[m]  = *(const short8*)(Ak0 + m * 512);
#pragma unroll
        for (int n = 0; n < 4; ++n) bv0[n] = *(const short8*)(Bk0 + n * 512);
        if (t + 1 < nt) {
            const int ko = (t + 1) * 64 + 32;
            GLD(sA0 + ko, &L[LIDX(cur ^ 1, 0, 0, 1) + dst8]);
            GLD(sA1 + ko, &L[LIDX(cur ^ 1, 0, 1, 1) + dst8]);
        }
        __builtin_amdgcn_s_barrier();
        asm volatile("s_waitcnt lgkmcnt(0)" ::: "memory");
        __builtin_amdgcn_sched_barrier(0);
        __builtin_amdgcn_s_setprio(1);
#pragma unroll
        for (int m = 0; m < 4; ++m)
#pragma unroll
            for (int n = 0; n < 4; ++n)
                acc[m][n] = MFMA_BF16(av[m], bv0[n], acc[m][n], 0, 0, 0);
        __builtin_amdgcn_s_setprio(0);
        __builtin_amdgcn_s_barrier();

        // phase 2: k0, mf4-7
#pragma unroll
        for (int m = 0; m < 4; ++m) av[m] = *(const short8*)(Ak0 + (4 + m) * 512);
        if (t + 1 < nt) {
            const int ko = (t + 1) * 64 + 32;
            GLD(sB0 + ko, &L[LIDX(cur ^ 1, 1, 0, 1) + dst8]);
            GLD(sB1 + ko, &L[LIDX(cur ^ 1, 1, 1, 1) + dst8]);
        }
        if (t + 1 < nt) { asm volatile("s_waitcnt vmcnt(8)" ::: "memory"); }
        else            { asm volatile("s_waitcnt vmcnt(0)" ::: "memory"); }
        __builtin_amdgcn_s_barrier();
        asm volatile("s_waitcnt lgkmcnt(0)" ::: "memory");
        __builtin_amdgcn_sched_barrier(0);
        __builtin_amdgcn_s_setprio(1);
#pragma unroll
        for (int m = 0; m < 4; ++m)
#pragma unroll
            for (int n = 0; n < 4; ++n)
                acc[4 + m][n] = MFMA_BF16(av[m], bv0[n], acc[4 + m][n], 0, 0, 0);
        __builtin_amdgcn_s_setprio(0);
        __builtin_amdgcn_s_barrier();

        // phase 3: k1, mf0-3
#pragma unroll
        for (int m = 0; m < 4; ++m) av[m]  = *(const short8*)(Ak1 + m * 512);
#pragma unroll
        for (int n = 0; n < 4; ++n) bv1[n] = *(const short8*)(Bk1 + n * 512);
        if (t + 2 < nt) {
            const int ko = (t + 2) * 64;
            GLD(sA0 + ko, &L[LIDX(cur, 0, 0, 0) + dst8]);
            GLD(sA1 + ko, &L[LIDX(cur, 0, 1, 0) + dst8]);
        }
        __builtin_amdgcn_s_barrier();
        asm volatile("s_waitcnt lgkmcnt(0)" ::: "memory");
        __builtin_amdgcn_sched_barrier(0);
        __builtin_amdgcn_s_setprio(1);
#pragma unroll
        for (int m = 0; m < 4; ++m)
#pragma unroll
            for (int n = 0; n < 4; ++n)
                acc[m][n] = MFMA_BF16(av[m], bv1[n], acc[m][n], 0, 0, 0);
        __builtin_amdgcn_s_setprio(0);
        __builtin_amdgcn_s_barrier();

        // phase 4: k1, mf4-7
#pragma unroll
        for (int m = 0; m < 4; ++m) av[m] = *(const short8*)(Ak1 + (4 + m) * 512);
        if (t + 2 < nt) {
            const int ko = (t + 2) * 64;
            GLD(sB0 + ko, &L[LIDX(cur, 1, 0, 0) + dst8]);
            GLD(sB1 + ko, &L[LIDX(cur, 1, 1, 0) + dst8]);
        }
        if (t + 1 < nt) {
            if (t + 2 < nt) { asm volatile("s_waitcnt vmcnt(8)" ::: "memory"); }
            else            { asm volatile("s_waitcnt vmcnt(4)" ::: "memory"); }
        }
        __builtin_amdgcn_s_barrier();
        asm volatile("s_waitcnt lgkmcnt(0)" ::: "memory");
        __builtin_amdgcn_sched_barrier(0);
        __builtin_amdgcn_s_setprio(1);
#pragma unroll
        for (int m = 0; m < 4; ++m)
#pragma unroll
            for (int n = 0; n < 4; ++n)
                acc[4 + m][n] = MFMA_BF16(av[m], bv1[n], acc[4 + m][n], 0, 0, 0);
        __builtin_amdgcn_s_setprio(0);
        __builtin_amdgcn_s_barrier();
    }
}

// QK projection on the 8-phase core: grid 256 x 512thr.
__global__ __launch_bounds__(512, 2) void qk_gemm256(const unsigned short* __restrict__ xb,
                                                     const unsigned short* __restrict__ wb,
                                                     unsigned short* __restrict__ Qb,
                                                     unsigned short* __restrict__ Kb) {
    __shared__ __align__(16) unsigned short L[16 * 4096];
    const int lane = threadIdx.x & 63, wave = threadIdx.x >> 6;
    const int wm = wave >> 2, wn = wave & 3;
    const int lo = lane & 15, hi = lane >> 4;

    const int wg  = (blockIdx.x & 7) * 32 + (blockIdx.x >> 3);
    const int bmA = wg >> 3;
    const int bnB = wg & 7;

    f32x4 acc[8][4] = {};
    core256(xb, wb, bmA, bnB, L, acc);

    unsigned short* O = (bnB < 4) ? Qb : Kb;
    const int rb = bmA * 256 + wm * 128 + hi * 4;
    const int cb = (bnB & 3) * 256 + wn * 64 + lo;
#pragma unroll
    for (int mf = 0; mf < 8; ++mf)
#pragma unroll
        for (int nf = 0; nf < 4; ++nf)
#pragma unroll
            for (int r = 0; r < 4; ++r)
                O[(size_t)(rb + mf * 16 + r) * D_DIM + (cb + nf * 16)] = f2bf(acc[mf][nf][r]);
}

// S scores on the 8-phase core -> bf16 output.  Grid 144.
__global__ __launch_bounds__(512, 2) void s_gemm256(const unsigned short* __restrict__ Qb,
                                                    const unsigned short* __restrict__ Kb,
                                                    unsigned short* __restrict__ Sb) {
    __shared__ __align__(16) unsigned short L[16 * 4096];
    const int lane = threadIdx.x & 63, wave = threadIdx.x >> 6;
    const int wm = wave >> 2, wn = wave & 3;
    const int lo = lane & 15, hi = lane >> 4;

    const int wg = (blockIdx.x & 7) * 18 + (blockIdx.x >> 3);
    const int z  = wg / 36;
    int i = wg % 36;
    int bm = 0;
    while (i >= bm + 1) { i -= (bm + 1); ++bm; }
    const int bn = i;

    const unsigned short* Ap = Qb + (size_t)z * T_SEQ * D_DIM;
    const unsigned short* Bp = Kb + (size_t)z * T_SEQ * D_DIM;
    f32x4 acc[8][4] = {};
    core256(Ap, Bp, bm, bn, L, acc);

    unsigned short* Sp = Sb + (size_t)z * T_SEQ * T_SEQ;
    const float scale = 0.03125f;
    const int rb = bm * 256 + wm * 128 + hi * 4;
    const int cb = bn * 256 + wn * 64 + lo;
#pragma unroll
    for (int mf = 0; mf < 8; ++mf)
#pragma unroll
        for (int nf = 0; nf < 4; ++nf)
#pragma unroll
            for (int r = 0; r < 4; ++r) {
                const int row = rb + mf * 16 + r;
                const int col = cb + nf * 16;
                if (col <= row) Sp[(size_t)row * T_SEQ + col] = f2bf(acc[mf][nf][r] * scale);
            }
}

// ---------------------------------------------------------------------------
// 128x128 core (r4-proven): depth-2 prefetch over 3 buffers, counted vmcnt,
// 2 barriers/K-step, T2 swizzle.  Used by vsm_kernel / pv_gemm.
// ---------------------------------------------------------------------------
__device__ __forceinline__ void gemm_core(const unsigned short* __restrict__ A,
                                          const unsigned short* __restrict__ B,
                                          int lda, int ldb, int bm, int bn, int kend,
                                          f32x4 acc[4][4]) {
    __shared__ __align__(16) unsigned short As[3][128 * 32];
    __shared__ __align__(16) unsigned short Bs[3][128 * 32];
    const int tid  = threadIdx.x;
    const int lane = tid & 63;
    const int wave = tid >> 6;
    const int wm   = (wave >> 1) * 64;
    const int wn   = (wave & 1) * 64;
    const int lo   = lane & 15;
    const int hi   = lane >> 4;
    const int r0   = tid >> 2;
    const int q0   = (((tid & 3) ^ ((r0 >> 1) & 3)) * 8);

    const unsigned short* Arow0 = A + (size_t)(bm * 128 + r0) * lda + q0;
    const unsigned short* Arow1 = A + (size_t)(bm * 128 + r0 + 64) * lda + q0;
    const unsigned short* Brow0 = B + (size_t)(bn * 128 + r0) * ldb + q0;
    const unsigned short* Brow1 = B + (size_t)(bn * 128 + r0 + 64) * ldb + q0;

#define STAGE(t, buf) do { const int kk_ = (t) << 5; \
        GLD(Arow0 + kk_, As[buf] + tid * 8); \
        GLD(Arow1 + kk_, As[buf] + (tid + 256) * 8); \
        GLD(Brow0 + kk_, Bs[buf] + tid * 8); \
        GLD(Brow1 + kk_, Bs[buf] + (tid + 256) * 8); } while (0)

    const int nt = kend >> 5;
    STAGE(0, 0);
    STAGE(1, 1);

    int aoff[4], boff[4];
#pragma unroll
    for (int m = 0; m < 4; ++m) {
        const int ra = wm + m * 16 + lo;
        const int rb = wn + m * 16 + lo;
        aoff[m] = ra * 32 + ((hi ^ ((ra >> 1) & 3)) * 8);
        boff[m] = rb * 32 + ((hi ^ ((rb >> 1) & 3)) * 8);
    }

    int cur = 0;
    for (int t = 0; t < nt; ++t) {
        __builtin_amdgcn_s_barrier();
        if (t + 2 < nt) {
            int nb = cur + 2; if (nb >= 3) nb -= 3;
            STAGE(t + 2, nb);
            asm volatile("s_waitcnt vmcnt(8)" ::: "memory");
        } else if (t + 1 < nt) {
            asm volatile("s_waitcnt vmcnt(4)" ::: "memory");
        } else {
            asm volatile("s_waitcnt vmcnt(0)" ::: "memory");
        }
        __builtin_amdgcn_s_barrier();
        __builtin_amdgcn_sched_barrier(0);

        short8 av[4], bv[4];
#pragma unroll
        for (int m = 0; m < 4; ++m) av[m] = *(const short8*)&As[cur][aoff[m]];
#pragma unroll
        for (int n = 0; n < 4; ++n) bv[n] = *(const short8*)&Bs[cur][boff[n]];
        asm volatile("s_waitcnt lgkmcnt(0)" ::: "memory");
        __builtin_amdgcn_sched_barrier(0);

        __builtin_amdgcn_s_setprio(1);
#pragma unroll
        for (int m = 0; m < 4; ++m)
#pragma unroll
            for (int n = 0; n < 4; ++n)
                acc[m][n] = MFMA_BF16(av[m], bv[n], acc[m][n], 0, 0, 0);
        __builtin_amdgcn_s_setprio(0);

        cur += 1; if (cur >= 3) cur = 0;
    }
#undef STAGE
}

// ===========================================================================
// Fused V^T projection + softmax: 2560 blocks x 256 thr.
//   d < 512 : V^T tile (same decode as the old v_gemm dim3(64,8) grid)
//   d >= 512: softmax row-group (4 rows/block, bf16 in / bf16 out) — streams
//             while the v-role GEMM blocks own the CUs (no panel locality to
//             destroy, unlike the failed r8 GEMM+GEMM fusion).
// ===========================================================================
__global__ __launch_bounds__(256) void vsm_kernel(const unsigned short* __restrict__ xb,
                                                  const unsigned short* __restrict__ wv,
                                                  unsigned short* __restrict__ Vt,
                                                  const unsigned short* __restrict__ Sb,
                                                  unsigned short* __restrict__ P) {
    const int d = blockIdx.x;
    const int lane = threadIdx.x & 63, wave = threadIdx.x >> 6;

    if (d < 512) {
        const int tb = d & 63;          // t-block 0..63
        const int eb = d >> 6;          // e-block 0..7
        f32x4 acc[4][4] = {};
        gemm_core(wv, xb, D_DIM, D_DIM, eb, tb, D_DIM, acc);
        const int rb = eb * 128 + (wave >> 1) * 64 + ((lane >> 4) << 2);   // e
        const int cb = tb * 128 + (wave & 1) * 64 + (lane & 15);           // t global
#pragma unroll
        for (int m = 0; m < 4; ++m)
#pragma unroll
            for (int n = 0; n < 4; ++n)
#pragma unroll
                for (int r = 0; r < 4; ++r) {
                    const int e = rb + m * 16 + r;
                    const int t = cb + n * 16;
                    Vt[((size_t)(t >> 11) * D_DIM + e) * T_SEQ + (t & 2047)] = f2bf(acc[m][n][r]);
                }
        return;
    }

    // ---- softmax role ----
    const int row = (d - 512) * 4 + wave;        // 0..8191
    const int b = row >> 11, i = row & 2047;
    const unsigned short* srow = Sb + ((size_t)b * T_SEQ + i) * T_SEQ;
    unsigned short* prow = P + ((size_t)b * T_SEQ + i) * T_SEQ;
    const int len = i + 1;
    const int padlen = ((i >> 7) + 1) * 128;     // pv reads cols < kend = padlen

    float f[4][8];
    float m = -1e30f;
#pragma unroll
    for (int c = 0; c < 4; ++c) {
        const int j0 = (c * 64 + lane) * 8;
        if (j0 < padlen) {
            short8 raw = *(const short8*)(srow + j0);
#pragma unroll
            for (int e = 0; e < 8; ++e) {
                f[c][e] = bf2f((unsigned short)raw[e]);
                if (j0 + e < len) m = fmaxf(m, f[c][e]);
            }
        }
    }
#pragma unroll
    for (int off = 32; off; off >>= 1) m = fmaxf(m, __shfl_xor(m, off, 64));

    float s = 0.f;
#pragma unroll
    for (int c = 0; c < 4; ++c) {
        const int j0 = (c * 64 + lane) * 8;
        if (j0 < padlen) {
#pragma unroll
            for (int e = 0; e < 8; ++e) {
                float ev = (j0 + e < len) ? __expf(f[c][e] - m) : 0.f;
                f[c][e] = ev;
                s += ev;
            }
        }
    }
#pragma unroll
    for (int off = 32; off; off >>= 1) s += __shfl_xor(s, off, 64);
    const float inv = 1.f / s;

#pragma unroll
    for (int c = 0; c < 4; ++c) {
        const int j0 = (c * 64 + lane) * 8;
        if (j0 < padlen) {
            short8 o;
#pragma unroll
            for (int e = 0; e < 8; ++e) o[e] = (short)f2bf(f[c][e] * inv);
            *(short8*)(prow + j0) = o;
        }
    }
}

// ===========================================================================
// pv split-K (r12-proven): 768 blocks, every co-scheduled triple sums to 68
// K-steps.  cat2 partials -> Ppart; pv_reduce adds them into Out.
// ===========================================================================
__global__ __launch_bounds__(256) void pv_gemm(const unsigned short* __restrict__ P,
                                               const unsigned short* __restrict__ Vt,
                                               float* __restrict__ Out,
                                               float* __restrict__ Ppart) {
    const int d = blockIdx.x;
    const int u = d & 255;
    const int k = u >> 5;                 // 0..7
    const int bn = (u >> 2) & 7;
    const int z  = u & 3;
    const int cat = d >> 8;               // 0,1,2

    int bm, kstart, klen;
    if (cat == 0) { bm = 7 - k;  kstart = 0;              klen = (bm + 1) * 128; }
    else          { bm = 8 + k;  const int h = (bm + 1) * 64;
                    kstart = (cat == 2) ? h : 0;          klen = h; }

    const unsigned short* Ap = P  + (size_t)z * T_SEQ * T_SEQ + kstart;
    const unsigned short* Bp = Vt + (size_t)z * D_DIM * T_SEQ + kstart;
    f32x4 acc[4][4] = {};
    gemm_core(Ap, Bp, T_SEQ, T_SEQ, bm, bn, klen, acc);

    const int lane = threadIdx.x & 63, wave = threadIdx.x >> 6;
    const int rb = bm * 128 + (wave >> 1) * 64 + ((lane >> 4) << 2);
    const int cb = bn * 128 + (wave & 1) * 64 + (lane & 15);
    if (cat < 2) {
        float* Op = Out + (size_t)z * T_SEQ * D_DIM;
#pragma unroll
        for (int m = 0; m < 4; ++m)
#pragma unroll
            for (int n = 0; n < 4; ++n)
#pragma unroll
                for (int r = 0; r < 4; ++r)
                    Op[(size_t)(rb + m * 16 + r) * D_DIM + (cb + n * 16)] = acc[m][n][r];
    } else {
        float* Pp = Ppart + (size_t)z * 1024 * D_DIM;
#pragma unroll
        for (int m = 0; m < 4; ++m)
#pragma unroll
            for (int n = 0; n < 4; ++n)
#pragma unroll
                for (int r = 0; r < 4; ++r)
                    Pp[(size_t)(rb - 1024 + m * 16 + r) * D_DIM + (cb + n * 16)] = acc[m][n][r];
    }
}

// Out rows 1024..2047 (per batch) += Ppart.
__global__ __launch_bounds__(256) void pv_reduce(float* __restrict__ Out,
                                                 const float* __restrict__ Ppart) {
    const int i = blockIdx.x * 256 + threadIdx.x;     // < 1048576 float4
    const int pf = i * 4;
    const int z = pf >> 20;
    const int r = (pf >> 10) & 1023;
    const int c = pf & 1023;
    f32x4 a = *(const f32x4*)(Ppart + (size_t)pf);
    float* op = Out + ((size_t)z * 2048 + 1024 + r) * 1024 + c;
    f32x4 b = *(const f32x4*)op;
    b[0] += a[0]; b[1] += a[1]; b[2] += a[2]; b[3] += a[3];
    *(f32x4*)op = b;
}

extern "C" void kernel_launch(void* const* d_in, const int* in_sizes, int n_in,
                              void* d_out, int out_size, void* d_ws, size_t ws_size,
                              hipStream_t stream) {
    const float* x  = (const float*)d_in[0];
    const float* Wq = (const float*)d_in[1];
    const float* Wk = (const float*)d_in[2];
    const float* Wv = (const float*)d_in[3];
    float* out = (float*)d_out;
    char* ws = (char*)d_ws;

    unsigned short* xb = (unsigned short*)(ws);                 // 16 MB  x bf16 [8192,1024]
    unsigned short* wb = (unsigned short*)(ws + 16777216);      // 6 MB   Wq|Wk|Wv bf16
    unsigned short* Qb = (unsigned short*)(ws + 23068672);      // 16 MB
    unsigned short* Kb = (unsigned short*)(ws + 39845888);      // 16 MB
    unsigned short* Vt = (unsigned short*)(ws + 56623104);      // 16 MB  V^T per batch [1024][2048]
    unsigned short* Sb = (unsigned short*)(ws + 73400320);      // 32 MB  scores bf16
    unsigned short* P  = (unsigned short*)(ws + 140509184);     // 32 MB  probs bf16
    float*       Ppart = (float*)(ws + 106954752);              // 16 MB  (after Sb, within old S region)
    (void)ws_size; (void)in_sizes; (void)n_in; (void)out_size;

    cast_all<<<11264, 256, 0, stream>>>((const float4*)x, (const float4*)Wq,
                                        (const float4*)Wk, (const float4*)Wv,
                                        (ushort4*)xb, (ushort4*)wb);

    qk_gemm256<<<256, 512, 0, stream>>>(xb, wb, Qb, Kb);
    s_gemm256<<<144, 512, 0, stream>>>(Qb, Kb, Sb);
    vsm_kernel<<<2560, 256, 0, stream>>>(xb, wb + 2097152, Vt, Sb, P);
    pv_gemm<<<768, 256, 0, stream>>>(P, Vt, out, Ppart);
    pv_reduce<<<4096, 256, 0, stream>>>(out, Ppart);
}